// Round 1
// baseline (181.110 us; speedup 1.0000x reference)
//
#include <hip/hip_runtime.h>
#include <math.h>

// x: (256, 2048, 25, 2) fp32, contiguous. weights: (2048, 1) fp32 — only w[0] used.
// out[b,f,j] = R^T-ish rotate for j<8, copy for j>=8.
// Flat float4 view: element i covers pairs 2i and 2i+1; joint = pair % 25.

__global__ void __launch_bounds__(256) rigid_rot_kernel(
    const float4* __restrict__ x,
    const float*  __restrict__ w,
    float4* __restrict__ out,
    int nvec)
{
    // wave-uniform scalar work, amortized over grid-stride loop
    const float theta = w[0];
    const float s = sinf(theta);
    const float c = cosf(theta);

    const int stride = gridDim.x * blockDim.x;
    for (int i = blockIdx.x * blockDim.x + threadIdx.x; i < nvec; i += stride) {
        float4 v = x[i];

        unsigned int p0 = 2u * (unsigned)i;      // first pair index in this float4
        unsigned int j0 = p0 % 25u;              // joint of pair 0 (magic-mul)
        unsigned int j1 = (j0 + 1u == 25u) ? 0u : j0 + 1u;  // joint of pair 1

        float4 r = v;
        if (j0 < 8u) {                           // predicated (short body)
            r.x = v.x * c + v.y * s;
            r.y = v.y * c - v.x * s;
        }
        if (j1 < 8u) {
            r.z = v.z * c + v.w * s;
            r.w = v.w * c - v.z * s;
        }
        out[i] = r;
    }
}

extern "C" void kernel_launch(void* const* d_in, const int* in_sizes, int n_in,
                              void* d_out, int out_size, void* d_ws, size_t ws_size,
                              hipStream_t stream)
{
    const float4* x = (const float4*)d_in[0];
    const float*  w = (const float*)d_in[1];
    float4* out = (float4*)d_out;

    const int nvec = out_size / 4;               // 26,214,400 / 4 = 6,553,600

    // 256 CUs; oversubscribe with grid-stride so sincos amortizes.
    const int block = 256;
    const int grid  = 4096;                      // ~16 blocks/CU worth of waves in flight
    rigid_rot_kernel<<<grid, block, 0, stream>>>(x, w, out, nvec);
}

// Round 3
// 175.663 us; speedup vs baseline: 1.0310x; 1.0310x over previous
//
#include <hip/hip_runtime.h>
#include <math.h>

// x: (256, 2048, 25, 2) fp32 contiguous = 26,214,400 floats = 6,553,600 float4.
// Only weights[0] used: single 2x2 rotation applied to joints 0..7, copy 8..24.
// out_x = x*c + y*s ; out_y = y*c - x*s  (R = [[c,-s],[s,c]], einsum bfjc,cd->bfjd)
//
// ILP scheme: total threads T = nvec/4; thread i handles float4s {i, i+T, i+2T, i+3T}
// -> 4 independent global_load_dwordx4 in flight per thread, coalesced per wave.
// nvec = 6,553,600 = 4 * 6400 blocks * 256 threads exactly: no tail, no loop.
//
// v4f (clang ext_vector_type) instead of HIP float4: __builtin_nontemporal_*
// requires a native vector type, HIP's float4 is a struct.

typedef float v4f __attribute__((ext_vector_type(4)));

__device__ __forceinline__ v4f rot_pair4(v4f v, unsigned int pair0,
                                         float c, float s)
{
    unsigned int j0 = pair0 % 25u;                       // joint of pair 0
    unsigned int j1 = (j0 + 1u == 25u) ? 0u : j0 + 1u;   // joint of pair 1
    v4f r = v;
    if (j0 < 8u) { r.x = v.x * c + v.y * s; r.y = v.y * c - v.x * s; }
    if (j1 < 8u) { r.z = v.z * c + v.w * s; r.w = v.w * c - v.z * s; }
    return r;
}

__global__ void __launch_bounds__(256) rigid_rot_kernel(
    const v4f* __restrict__ x,
    const float* __restrict__ w,
    v4f* __restrict__ out,
    int T)                                // total thread count = nvec/4
{
    const float theta = w[0];
    const float s = sinf(theta);
    const float c = cosf(theta);

    const int i0 = blockIdx.x * blockDim.x + threadIdx.x;
    const int i1 = i0 + T;
    const int i2 = i0 + 2 * T;
    const int i3 = i0 + 3 * T;

    // 4 independent loads -> 4 outstanding vmem ops before first use
    v4f v0 = __builtin_nontemporal_load(&x[i0]);
    v4f v1 = __builtin_nontemporal_load(&x[i1]);
    v4f v2 = __builtin_nontemporal_load(&x[i2]);
    v4f v3 = __builtin_nontemporal_load(&x[i3]);

    v4f r0 = rot_pair4(v0, 2u * (unsigned)i0, c, s);
    v4f r1 = rot_pair4(v1, 2u * (unsigned)i1, c, s);
    v4f r2 = rot_pair4(v2, 2u * (unsigned)i2, c, s);
    v4f r3 = rot_pair4(v3, 2u * (unsigned)i3, c, s);

    // streaming output, zero reuse -> nontemporal to skip L2 write-allocate
    __builtin_nontemporal_store(r0, &out[i0]);
    __builtin_nontemporal_store(r1, &out[i1]);
    __builtin_nontemporal_store(r2, &out[i2]);
    __builtin_nontemporal_store(r3, &out[i3]);
}

extern "C" void kernel_launch(void* const* d_in, const int* in_sizes, int n_in,
                              void* d_out, int out_size, void* d_ws, size_t ws_size,
                              hipStream_t stream)
{
    const v4f* x = (const v4f*)d_in[0];
    const float* w = (const float*)d_in[1];
    v4f* out = (v4f*)d_out;

    const int nvec = out_size / 4;        // 6,553,600
    const int T    = nvec / 4;            // 1,638,400 threads, 4 float4 each
    const int block = 256;
    const int grid  = T / block;          // 6400 blocks (exact)

    rigid_rot_kernel<<<grid, block, 0, stream>>>(x, w, out, T);
}